// Round 1
// baseline (890.163 us; speedup 1.0000x reference)
//
#include <hip/hip_runtime.h>
#include <hip/hip_bf16.h>

#define HEADS 3

// ---------------------------------------------------------------- prep: ce[h] = sum_d We[h*D+d] * ae[h*D+d]
__global__ void prep_ce_kernel(const float* __restrict__ We1, const float* __restrict__ ae1,
                               const float* __restrict__ We2, const float* __restrict__ ae2,
                               const float* __restrict__ We3, const float* __restrict__ ae3,
                               float* __restrict__ ce) {
    int t = threadIdx.x;
    if (t >= 9) return;
    int l = t / 3, h = t % 3;
    const float* We = (l == 0) ? We1 : (l == 1) ? We2 : We3;
    const float* ae = (l == 0) ? ae1 : (l == 1) ? ae2 : ae3;
    int D = (l == 0) ? 8 : (l == 1) ? 16 : 32;
    float s = 0.f;
    for (int d = 0; d < D; d++) s += We[h * D + d] * ae[h * D + d];
    ce[t] = s;
}

// ---------------------------------------------------------------- CSR build
__global__ void hist_kernel(const int* __restrict__ dst, int* __restrict__ deg, int E) {
    int tid = blockIdx.x * blockDim.x + threadIdx.x;
    if (tid < E) atomicAdd(&deg[dst[tid]], 1);
}

__global__ void scan_kernel(const int* __restrict__ deg, int* __restrict__ row_ptr, int N) {
    __shared__ int sums[1024];
    int t = threadIdx.x;
    int C = (N + 1023) / 1024;
    int begi = t * C;
    int endi = begi + C; if (endi > N) endi = N;
    int s = 0;
    for (int i = begi; i < endi; i++) s += deg[i];
    sums[t] = s;
    __syncthreads();
    // Hillis-Steele inclusive scan over 1024 entries
    for (int off = 1; off < 1024; off <<= 1) {
        int v = (t >= off) ? sums[t - off] : 0;
        __syncthreads();
        sums[t] += v;
        __syncthreads();
    }
    int run = sums[t] - s;  // exclusive prefix of this chunk
    for (int i = begi; i < endi; i++) { row_ptr[i] = run; run += deg[i]; }
    if (t == 1023) row_ptr[N] = sums[1023];
}

__global__ void scatter_kernel(const int* __restrict__ src, const int* __restrict__ dst,
                               const float* __restrict__ ef, const int* __restrict__ row_ptr,
                               int* __restrict__ cnt, int* __restrict__ ssrc,
                               float* __restrict__ sef, int E) {
    int tid = blockIdx.x * blockDim.x + threadIdx.x;
    if (tid >= E) return;
    int d = dst[tid];
    int pos = row_ptr[d] + atomicAdd(&cnt[d], 1);
    ssrc[pos] = src[tid];
    sef[pos] = ef[tid];
}

// ---------------------------------------------------------------- node projection: ft, el, er
template <int FIN, int D, bool MEAN_PREV>
__global__ void node_kernel(const float* __restrict__ xin,   // node_feats [N,FIN] or prev out [N,3,FIN]
                            const float* __restrict__ W,     // [3*D, FIN]
                            const float* __restrict__ al,    // [3*D]
                            const float* __restrict__ ar,    // [3*D]
                            float* __restrict__ ft,          // [N,3,D]
                            float* __restrict__ el, float* __restrict__ er,  // [N,3]
                            int N) {
    int tid = blockIdx.x * blockDim.x + threadIdx.x;
    if (tid >= N * HEADS) return;
    int n = tid / HEADS, h = tid % HEADS;
    float x[FIN];
    if (MEAN_PREV) {
        #pragma unroll
        for (int k = 0; k < FIN; k++)
            x[k] = (xin[(n * HEADS + 0) * FIN + k] +
                    xin[(n * HEADS + 1) * FIN + k] +
                    xin[(n * HEADS + 2) * FIN + k]) * (1.0f / 3.0f);
    } else {
        #pragma unroll
        for (int k = 0; k < FIN; k++) x[k] = xin[n * FIN + k];
    }
    float e_l = 0.f, e_r = 0.f;
    #pragma unroll
    for (int d = 0; d < D; d++) {
        const float* wr = &W[(h * D + d) * FIN];
        float f = 0.f;
        #pragma unroll
        for (int k = 0; k < FIN; k++) f += x[k] * wr[k];
        ft[(n * HEADS + h) * D + d] = f;
        e_l += f * al[h * D + d];
        e_r += f * ar[h * D + d];
    }
    el[tid] = e_l;
    er[tid] = e_r;
}

// ---------------------------------------------------------------- attention + aggregate (per dst node, per head)
template <int D>
__global__ void agg_kernel(const int* __restrict__ row_ptr, const int* __restrict__ ssrc,
                           const float* __restrict__ sef, const float* __restrict__ ft,
                           const float* __restrict__ el, const float* __restrict__ er,
                           const float* __restrict__ ce,   // [3] for this layer
                           const float* __restrict__ b,    // [3*D]
                           float* __restrict__ out,        // [N,3,D], bias added
                           int N) {
    int tid = blockIdx.x * blockDim.x + threadIdx.x;
    if (tid >= N * HEADS) return;
    int n = tid / HEADS, h = tid % HEADS;
    int beg = row_ptr[n], end = row_ptr[n + 1];
    float ernh = er[tid];
    float ceh = ce[h];
    float m = -3.0e38f;
    for (int e = beg; e < end; e++) {
        float ev = el[ssrc[e] * HEADS + h] + ernh + sef[e] * ceh;
        ev = ev > 0.f ? ev : 0.2f * ev;   // leaky_relu slope 0.2
        m = fmaxf(m, ev);
    }
    float ssum = 0.f;
    float msg[D];
    #pragma unroll
    for (int d = 0; d < D; d++) msg[d] = 0.f;
    for (int e = beg; e < end; e++) {
        int s = ssrc[e];
        float ev = el[s * HEADS + h] + ernh + sef[e] * ceh;
        ev = ev > 0.f ? ev : 0.2f * ev;
        float ex = __expf(ev - m);
        ssum += ex;
        const float* fr = &ft[(s * HEADS + h) * D];
        #pragma unroll
        for (int d = 0; d < D; d++) msg[d] += ex * fr[d];
    }
    float inv = 1.0f / fmaxf(ssum, 1e-9f);
    #pragma unroll
    for (int d = 0; d < D; d++) out[tid * D + d] = msg[d] * inv + b[h * D + d];
}

// ---------------------------------------------------------------- MLP head + global max
__global__ void mlp_max_kernel(const float* __restrict__ h3,  // [N,3,32] (bias included)
                               const float* __restrict__ l1w, const float* __restrict__ l1b,
                               const float* __restrict__ l2w, const float* __restrict__ l2b,
                               const float* __restrict__ l3w, const float* __restrict__ l3b,
                               const float* __restrict__ l4w, const float* __restrict__ l4b,
                               unsigned int* __restrict__ maxkey, int N) {
    int tid = blockIdx.x * blockDim.x + threadIdx.x;
    float feat = -3.0e38f;
    if (tid < N) {
        float acc = l4b[0];
        #pragma unroll
        for (int h = 0; h < HEADS; h++) {
            const float* v = &h3[(tid * HEADS + h) * 32];
            float y1[16];
            #pragma unroll
            for (int i = 0; i < 16; i++) {
                float s = l1b[i];
                const float* w = &l1w[i * 32];
                #pragma unroll
                for (int k = 0; k < 32; k++) s += v[k] * w[k];
                y1[i] = s > 0.f ? s : 0.01f * s;
            }
            float y2[4];
            #pragma unroll
            for (int i = 0; i < 4; i++) {
                float s = l2b[i];
                const float* w = &l2w[i * 16];
                #pragma unroll
                for (int k = 0; k < 16; k++) s += y1[k] * w[k];
                y2[i] = s > 0.f ? s : 0.01f * s;
            }
            float y3 = l3b[0];
            #pragma unroll
            for (int k = 0; k < 4; k++) y3 += y2[k] * l3w[k];
            acc += y3 * l4w[h];
        }
        feat = acc;
    }
    // wave-64 max reduce
    #pragma unroll
    for (int off = 32; off > 0; off >>= 1)
        feat = fmaxf(feat, __shfl_down(feat, off));
    if ((threadIdx.x & 63) == 0) {
        unsigned int u = __float_as_uint(feat);
        unsigned int key = (u & 0x80000000u) ? ~u : (u | 0x80000000u);
        atomicMax(maxkey, key);
    }
}

__global__ void finalize_kernel(const unsigned int* __restrict__ maxkey, float* __restrict__ out) {
    unsigned int key = *maxkey;
    unsigned int u = (key & 0x80000000u) ? (key & 0x7FFFFFFFu) : ~key;
    out[0] = __uint_as_float(u);
}

// ----------------------------------------------------------------
extern "C" void kernel_launch(void* const* d_in, const int* in_sizes, int n_in,
                              void* d_out, int out_size, void* d_ws, size_t ws_size,
                              hipStream_t stream) {
    const float* node_feats = (const float*)d_in[0];
    const float* edge_feats = (const float*)d_in[1];
    const int* src = (const int*)d_in[2];
    const int* dst = (const int*)d_in[3];
    const float* W1  = (const float*)d_in[4];
    const float* We1 = (const float*)d_in[5];
    const float* al1 = (const float*)d_in[6];
    const float* ar1 = (const float*)d_in[7];
    const float* ae1 = (const float*)d_in[8];
    const float* b1  = (const float*)d_in[9];
    const float* W2  = (const float*)d_in[10];
    const float* We2 = (const float*)d_in[11];
    const float* al2 = (const float*)d_in[12];
    const float* ar2 = (const float*)d_in[13];
    const float* ae2 = (const float*)d_in[14];
    const float* b2  = (const float*)d_in[15];
    const float* W3  = (const float*)d_in[16];
    const float* We3 = (const float*)d_in[17];
    const float* al3 = (const float*)d_in[18];
    const float* ar3 = (const float*)d_in[19];
    const float* ae3 = (const float*)d_in[20];
    const float* b3  = (const float*)d_in[21];
    const float* l1w = (const float*)d_in[22];
    const float* l1b = (const float*)d_in[23];
    const float* l2w = (const float*)d_in[24];
    const float* l2b = (const float*)d_in[25];
    const float* l3w = (const float*)d_in[26];
    const float* l3b = (const float*)d_in[27];
    const float* l4w = (const float*)d_in[28];
    const float* l4b = (const float*)d_in[29];

    const int N = in_sizes[0] / 6;
    const int E = in_sizes[2];

    char* ws = (char*)d_ws;
    size_t off = 0;
    auto alloc = [&](size_t bytes) -> void* {
        void* p = ws + off;
        off = (off + bytes + 255) & ~(size_t)255;
        return p;
    };
    int* deg            = (int*)alloc((size_t)N * 4);
    int* cnt            = (int*)alloc((size_t)N * 4);
    unsigned int* mkey  = (unsigned int*)alloc(4);
    size_t zero_bytes   = off;  // deg + cnt + maxkey
    int* row_ptr        = (int*)alloc((size_t)(N + 1) * 4);
    int* ssrc           = (int*)alloc((size_t)E * 4);
    float* sef          = (float*)alloc((size_t)E * 4);
    float* ft           = (float*)alloc((size_t)N * 96 * 4);
    float* outb         = (float*)alloc((size_t)N * 96 * 4);
    float* el           = (float*)alloc((size_t)N * 3 * 4);
    float* er           = (float*)alloc((size_t)N * 3 * 4);
    float* ce           = (float*)alloc(9 * 4);

    hipMemsetAsync(d_ws, 0, zero_bytes, stream);

    prep_ce_kernel<<<1, 16, 0, stream>>>(We1, ae1, We2, ae2, We3, ae3, ce);
    hist_kernel<<<(E + 255) / 256, 256, 0, stream>>>(dst, deg, E);
    scan_kernel<<<1, 1024, 0, stream>>>(deg, row_ptr, N);
    scatter_kernel<<<(E + 255) / 256, 256, 0, stream>>>(src, dst, edge_feats, row_ptr, cnt,
                                                        ssrc, sef, E);

    const int NH = N * HEADS;
    const int gb = (NH + 255) / 256;

    // layer 1: 6 -> 8
    node_kernel<6, 8, false><<<gb, 256, 0, stream>>>(node_feats, W1, al1, ar1, ft, el, er, N);
    agg_kernel<8><<<gb, 256, 0, stream>>>(row_ptr, ssrc, sef, ft, el, er, ce + 0, b1, outb, N);
    // layer 2: mean(8) -> 16
    node_kernel<8, 16, true><<<gb, 256, 0, stream>>>(outb, W2, al2, ar2, ft, el, er, N);
    agg_kernel<16><<<gb, 256, 0, stream>>>(row_ptr, ssrc, sef, ft, el, er, ce + 3, b2, outb, N);
    // layer 3: mean(16) -> 32
    node_kernel<16, 32, true><<<gb, 256, 0, stream>>>(outb, W3, al3, ar3, ft, el, er, N);
    agg_kernel<32><<<gb, 256, 0, stream>>>(row_ptr, ssrc, sef, ft, el, er, ce + 6, b3, outb, N);

    // MLP head + global max
    mlp_max_kernel<<<(N + 255) / 256, 256, 0, stream>>>(outb, l1w, l1b, l2w, l2b, l3w, l3b,
                                                        l4w, l4b, mkey, N);
    finalize_kernel<<<1, 1, 0, stream>>>(mkey, (float*)d_out);
}